// Round 12
// baseline (400.960 us; speedup 1.0000x reference)
//
#include <hip/hip_runtime.h>
#include <hip/hip_fp16.h>
#include <hip/hip_cooperative_groups.h>

#define IN_CH 128
#define HID 48
#define OUT_CH 16
#define NEG_SLOPE 0.2f
#define SCAN_ELEMS 2048   // per chunk: 256 threads x 8
#define ROWB 128          // padded h2 row stride in bytes (48 halves + 16 pad)
#define WLP 20            // lin_W LDS pad: 240*slot%32 in {0,16} -> 2-way = free

__device__ __forceinline__ float leaky(float x) { return x >= 0.f ? x : NEG_SLOPE * x; }
__device__ __forceinline__ float elu(float x) { return x > 0.f ? x : __expf(x) - 1.f; }

__device__ __forceinline__ void load_edge(const void* ei, int E, int is64, int e,
                                          int& s, int& d) {
    if (is64) {
        const long long* p = (const long long*)ei;
        s = (int)p[e];
        d = (int)p[(size_t)E + e];
    } else {
        const int* p = (const int*)ei;
        s = p[e];
        d = p[(size_t)E + e];
    }
}

// K1: h = x @ W (fp16, 128B-padded rows) fused with a_src/a_dst, deg zeroing,
// and the int64/int32 edge_index probe (block 0).
#define BLK_NODES 256
__global__ __launch_bounds__(256, 2) void k_xw(const float* __restrict__ x,
                                               const float* __restrict__ W,
                                               const float* __restrict__ att_src,
                                               const float* __restrict__ att_dst,
                                               const unsigned* __restrict__ ei,
                                               __half* __restrict__ h2,
                                               float* __restrict__ a_src,
                                               float* __restrict__ a_dst,
                                               int* __restrict__ deg,
                                               int* __restrict__ flag, int N) {
    __shared__ float Wl[IN_CH * HID];
    __shared__ float xl[BLK_NODES * 33];
    const int t = threadIdx.x;
    if (blockIdx.x == 0 && t == 0) {
        unsigned sdet = 0;
        for (int i = 1; i < 128; i += 2) sdet |= ei[i];
        *flag = (sdet == 0) ? 1 : 0;
    }
    for (int i = t; i < IN_CH * HID / 4; i += 256)
        ((float4*)Wl)[i] = ((const float4*)W)[i];
    const int n0 = blockIdx.x * BLK_NODES;
    const int kq = t & 3;
    const int ng = t >> 2;
    const int k0 = kq * 12;

    float acc[4][12];
#pragma unroll
    for (int i = 0; i < 4; ++i)
#pragma unroll
        for (int j = 0; j < 12; ++j) acc[i][j] = 0.f;

    for (int c0 = 0; c0 < IN_CH; c0 += 32) {
        __syncthreads();
#pragma unroll
        for (int p = 0; p < 8; ++p) {
            int id = t + p * 256;
            int row = id >> 3;
            int seg = id & 7;
            int n = n0 + row;
            float4 v = make_float4(0.f, 0.f, 0.f, 0.f);
            if (n < N) v = ((const float4*)(x + (size_t)n * IN_CH + c0))[seg];
            float* dst = &xl[row * 33 + seg * 4];
            dst[0] = v.x; dst[1] = v.y; dst[2] = v.z; dst[3] = v.w;
        }
        __syncthreads();
#pragma unroll 8
        for (int cc = 0; cc < 32; ++cc) {
            int c = c0 + cc;
            float xv[4];
#pragma unroll
            for (int i = 0; i < 4; ++i) xv[i] = xl[(ng * 4 + i) * 33 + cc];
            const float* wr = &Wl[c * HID + k0];
#pragma unroll
            for (int j = 0; j < 12; ++j) {
                float wv = wr[j];
#pragma unroll
                for (int i = 0; i < 4; ++i) acc[i][j] += xv[i] * wv;
            }
        }
    }
#pragma unroll
    for (int i = 0; i < 4; ++i) {
        int n = n0 + ng * 4 + i;
        if (n < N) {
            uint* dst = (uint*)((char*)h2 + (size_t)n * ROWB) + k0 / 2;
#pragma unroll
            for (int j = 0; j < 6; ++j) {
                __half2 hv = __floats2half2_rn(acc[i][2 * j], acc[i][2 * j + 1]);
                dst[j] = *(const uint*)&hv;
            }
        }
    }
    // zero the 32B row padding (halves 48..63)
#pragma unroll
    for (int p = 0; p < 8; ++p) {
        int id = t + p * 256;
        int row = id >> 3;
        int seg = id & 7;
        int n = n0 + row;
        if (n < N) ((uint*)((char*)h2 + (size_t)n * ROWB))[24 + seg] = 0u;
    }
    // fused attention terms
    float as_[4], ad_[4];
#pragma unroll
    for (int i = 0; i < 4; ++i) {
        float s1 = 0.f, s2 = 0.f;
#pragma unroll
        for (int j = 0; j < 12; ++j) {
            float a = acc[i][j];
            s1 += a * att_src[k0 + j];
            s2 += a * att_dst[k0 + j];
        }
        s1 += __shfl_xor(s1, 1); s1 += __shfl_xor(s1, 2);
        s2 += __shfl_xor(s2, 1); s2 += __shfl_xor(s2, 2);
        as_[i] = s1; ad_[i] = s2;
    }
    if (kq == 0) {
#pragma unroll
        for (int i = 0; i < 4; ++i) {
            int n = n0 + ng * 4 + i;
            if (n < N) { a_src[n] = as_[i]; a_dst[n] = ad_[i]; }
        }
    }
    {
        int n = n0 + t;
        if (n < N) deg[n] = 0;
    }
}

// K2 (cooperative, 512 blocks co-resident): full CSR build in one launch.
// phase1 count+rank -> sync -> phase2 chunk scan -> sync -> phase3 bsum scan
// -> sync -> phase4 scatter (pos = rowptr_local[d] + pre[chunk] + rank[e]).
// rowptr stays chunk-local; consumers add pre[] on the fly.
__global__ __launch_bounds__(256, 2) void k_csr(const void* __restrict__ ei,
                                                const int* __restrict__ flag,
                                                int* __restrict__ deg,
                                                int* __restrict__ rowptr,
                                                int* __restrict__ bsum,
                                                int* __restrict__ pre,
                                                unsigned short* __restrict__ rank,
                                                unsigned* __restrict__ srcs,
                                                int N, int E) {
    cooperative_groups::grid_group grid = cooperative_groups::this_grid();
    const int t = threadIdx.x;
    const int b = blockIdx.x;
    const int gid = b * 256 + t;
    const int nthr = gridDim.x * 256;
    const int is64 = *flag;
    const int nchunks = (N + SCAN_ELEMS - 1) / SCAN_ELEMS;

    // phase1: in-degree count (dst half only); atomic return = rank
    for (int e = gid; e < E; e += nthr) {
        int d = is64 ? (int)((const long long*)ei)[(size_t)E + e]
                     : ((const int*)ei)[(size_t)E + e];
        rank[e] = (unsigned short)atomicAdd(&deg[d], 1);
    }
    grid.sync();

    // phase2: per-chunk exclusive scan of deg -> rowptr (chunk-local)
    if (b < nchunks) {
        __shared__ int sm[256];
        const int base = b * SCAN_ELEMS + t * 8;
        int v[8];
        int s = 0;
#pragma unroll
        for (int i = 0; i < 8; ++i) {
            v[i] = (base + i < N) ? deg[base + i] : 0;
            s += v[i];
        }
        sm[t] = s;
        __syncthreads();
        for (int off = 1; off < 256; off <<= 1) {
            int y = (t >= off) ? sm[t - off] : 0;
            __syncthreads();
            sm[t] += y;
            __syncthreads();
        }
        int run = sm[t] - s;
#pragma unroll
        for (int i = 0; i < 8; ++i) {
            if (base + i < N) rowptr[base + i] = run;
            else if (base + i == N) rowptr[N] = run;   // local prefix at N
            run += v[i];
        }
        if (t == 255) bsum[b] = sm[255];
    }
    grid.sync();

    // phase3: scan the chunk totals
    if (b == 0 && t == 0) {
        int run = 0;
        for (int j = 0; j < nchunks; ++j) { pre[j] = run; run += bsum[j]; }
        pre[nchunks] = run;                 // == E
        if ((N & (SCAN_ELEMS - 1)) == 0) rowptr[N] = 0;
    }
    grid.sync();

    // phase4: scatter src ids (deterministic rank-based positions)
    for (int e = gid; e < E; e += nthr) {
        int s, d;
        load_edge(ei, E, is64, e, s, d);
        int pos = rowptr[d] + pre[d / SCAN_ELEMS] + (int)rank[e];
        __builtin_nontemporal_store((unsigned)s, srcs + pos);
    }
}

// K3: fused per-node aggregation + elu + linear + log_softmax. One wave per
// node, 4 waves/block; LDS-staged (ev,src) per 64-edge chunk; 4 slots x 16
// lanes, lane c owns bytes 8c..8c+7 of the padded row. rowptr is chunk-local;
// pre[] applied here.
__global__ __launch_bounds__(256) void k_gat_node(const int* __restrict__ rowptr,
                                                  const int* __restrict__ pre,
                                                  const unsigned* __restrict__ srcs,
                                                  const float* __restrict__ a_src,
                                                  const float* __restrict__ a_dst,
                                                  const __half* __restrict__ h2,
                                                  const float* __restrict__ gat_bias,
                                                  const float* __restrict__ lin_W,
                                                  const float* __restrict__ lin_b,
                                                  float* __restrict__ out, int N) {
    __shared__ float Wl[HID * WLP];
    __shared__ float lb[OUT_CH];
    __shared__ float gb[HID];
    __shared__ float o_sm[4][HID];
    __shared__ unsigned long long evb[4][64];
    const int t = threadIdx.x;
    for (int i = t; i < HID * OUT_CH; i += 256) Wl[(i >> 4) * WLP + (i & 15)] = lin_W[i];
    if (t < OUT_CH) lb[t] = lin_b[t];
    if (t >= 64 && t < 64 + HID) gb[t - 64] = gat_bias[t - 64];
    __syncthreads();

    const int wv = t >> 6;
    const int lane = t & 63;
    const int slot = lane >> 4;
    const int c = lane & 15;
    const int n = blockIdx.x * 4 + wv;
    const bool active = n < N;

    if (active) {
        const int base = rowptr[n] + pre[n / SCAN_ELEMS];
        const int deg = rowptr[n + 1] + pre[(n + 1) / SCAN_ELEMS] - base;
        const float adn = a_dst[n];
        const float ev_self = __expf(fminf(leaky(a_src[n] + adn), 50.f));
        const char* hb = (const char*)h2;

        float a0 = 0.f, a1 = 0.f, a2 = 0.f, a3 = 0.f;
        float evsum = (lane == 0) ? ev_self : 0.f;
        if (slot == 0) {
            uint2 hv = *(const uint2*)(hb + (size_t)n * ROWB + 8 * c);
            __half2 h01 = *(const __half2*)&hv.x;
            __half2 h23 = *(const __half2*)&hv.y;
            a0 = ev_self * __low2float(h01);
            a1 = ev_self * __high2float(h01);
            a2 = ev_self * __low2float(h23);
            a3 = ev_self * __high2float(h23);
        }
        for (int c0 = 0; c0 < deg; c0 += 64) {
            int j = c0 + lane;
            unsigned s = 0;
            float ev = 0.f;
            if (j < deg) {
                s = srcs[base + j];
                ev = __expf(fminf(leaky(a_src[s] + adn), 50.f));
            }
            evsum += ev;
            evb[wv][lane] = ((unsigned long long)__float_as_uint(ev) << 32) | s;
            const int cnt = (deg - c0 < 64) ? (deg - c0) : 64;
#pragma unroll 4
            for (int jj = slot; jj < cnt; jj += 4) {
                unsigned long long pr = evb[wv][jj];
                unsigned sj = (unsigned)pr;
                float evj = __uint_as_float((unsigned)(pr >> 32));
                uint2 hv = *(const uint2*)(hb + (size_t)sj * ROWB + 8 * c);
                __half2 h01 = *(const __half2*)&hv.x;
                __half2 h23 = *(const __half2*)&hv.y;
                a0 += evj * __low2float(h01);
                a1 += evj * __high2float(h01);
                a2 += evj * __low2float(h23);
                a3 += evj * __high2float(h23);
            }
        }
#pragma unroll
        for (int off = 1; off < 64; off <<= 1) evsum += __shfl_xor(evsum, off);
        a0 += __shfl_xor(a0, 16); a0 += __shfl_xor(a0, 32);
        a1 += __shfl_xor(a1, 16); a1 += __shfl_xor(a1, 32);
        a2 += __shfl_xor(a2, 16); a2 += __shfl_xor(a2, 32);
        a3 += __shfl_xor(a3, 16); a3 += __shfl_xor(a3, 32);
        const float inv = 1.f / evsum;
        if (slot == 0 && c < 12) {
            float4 v = make_float4(elu(a0 * inv + gb[4 * c + 0]),
                                   elu(a1 * inv + gb[4 * c + 1]),
                                   elu(a2 * inv + gb[4 * c + 2]),
                                   elu(a3 * inv + gb[4 * c + 3]));
            *(float4*)&o_sm[wv][4 * c] = v;
        }
    }
    __syncthreads();

    if (active) {
        const float* o = o_sm[wv];
        float z = 0.f;
#pragma unroll
        for (int i = 0; i < 12; ++i) {
            int k = 12 * slot + i;
            z += o[k] * Wl[k * WLP + c];
        }
        z += __shfl_xor(z, 16); z += __shfl_xor(z, 32);
        z += lb[c];
        float mx = z;
#pragma unroll
        for (int off = 8; off; off >>= 1) mx = fmaxf(mx, __shfl_xor(mx, off, 16));
        float ev = __expf(z - mx);
#pragma unroll
        for (int off = 8; off; off >>= 1) ev += __shfl_xor(ev, off, 16);
        float lse = mx + __logf(ev);
        if (slot == 0) out[(size_t)n * OUT_CH + c] = z - lse;
    }
}

extern "C" void kernel_launch(void* const* d_in, const int* in_sizes, int n_in,
                              void* d_out, int out_size, void* d_ws, size_t ws_size,
                              hipStream_t stream) {
    const float* x = (const float*)d_in[0];
    const void* edge_index = d_in[1];
    const float* W = (const float*)d_in[2];
    const float* att_src = (const float*)d_in[3];
    const float* att_dst = (const float*)d_in[4];
    const float* gat_bias = (const float*)d_in[5];
    const float* lin_W = (const float*)d_in[6];
    const float* lin_b = (const float*)d_in[7];
    float* out = (float*)d_out;

    const int N = in_sizes[0] / IN_CH;
    const int E = in_sizes[1] / 2;

    __half* h2 = (__half*)d_ws;                    // N rows x 128B (12.8MB)
    float* a_src = (float*)((char*)d_ws + (size_t)N * ROWB);  // N
    float* a_dst = a_src + N;                      // N
    int* rowptr = (int*)(a_dst + N);               // N+1 (chunk-local)
    int* degbuf = rowptr + N + 1;                  // N
    int* bsum = degbuf + N;                        // 64
    int* pre = bsum + 64;                          // 65
    int* flag = pre + 65;                          // 1
    unsigned short* rank = (unsigned short*)(flag + 1);       // E
    unsigned* srcs =
        (unsigned*)(((uintptr_t)(rank + E) + 3) & ~(uintptr_t)3);  // E x 4B

    k_xw<<<(N + BLK_NODES - 1) / BLK_NODES, 256, 0, stream>>>(
        x, W, att_src, att_dst, (const unsigned*)edge_index,
        h2, a_src, a_dst, degbuf, flag, N);

    {
        const void* eiv = edge_index;
        int Nv = N, Ev = E;
        void* cargs[] = {(void*)&eiv, (void*)&flag, (void*)&degbuf, (void*)&rowptr,
                         (void*)&bsum, (void*)&pre, (void*)&rank, (void*)&srcs,
                         (void*)&Nv, (void*)&Ev};
        hipLaunchCooperativeKernel((const void*)k_csr, dim3(512), dim3(256),
                                   cargs, 0, stream);
    }

    k_gat_node<<<(N + 3) / 4, 256, 0, stream>>>(rowptr, pre, srcs, a_src, a_dst,
                                                h2, gat_bias, lin_W, lin_b, out, N);
}

// Round 13
// 208.228 us; speedup vs baseline: 1.9256x; 1.9256x over previous
//
#include <hip/hip_runtime.h>
#include <hip/hip_fp16.h>

#define IN_CH 128
#define HID 48
#define OUT_CH 16
#define NEG_SLOPE 0.2f
#define SCAN_ELEMS 2048   // per block: 256 threads x 8
#define ROWB 128          // padded h2 row stride in bytes (48 halves + 16 pad)
#define WLP 20            // lin_W LDS pad: 240*slot%32 in {0,16} -> 2-way = free

__device__ __forceinline__ float leaky(float x) { return x >= 0.f ? x : NEG_SLOPE * x; }
__device__ __forceinline__ float elu(float x) { return x > 0.f ? x : __expf(x) - 1.f; }

// Edge index fetch that tolerates either int32 or int64 storage.
__device__ __forceinline__ void load_edge(const void* ei, int E, int is64, int e,
                                          int& s, int& d) {
    if (is64) {
        const long long* p = (const long long*)ei;
        s = (int)p[e];
        d = (int)p[(size_t)E + e];
    } else {
        const int* p = (const int*)ei;
        s = p[e];
        d = p[(size_t)E + e];
    }
}

// K1: h = x @ W (stored fp16, 128B-padded rows) fused with a_src/a_dst, deg
// zeroing, and the int64/int32 edge_index probe (block 0).
#define BLK_NODES 256
__global__ __launch_bounds__(256, 2) void k_xw(const float* __restrict__ x,
                                               const float* __restrict__ W,
                                               const float* __restrict__ att_src,
                                               const float* __restrict__ att_dst,
                                               const unsigned* __restrict__ ei,
                                               __half* __restrict__ h2,
                                               float* __restrict__ a_src,
                                               float* __restrict__ a_dst,
                                               int* __restrict__ deg,
                                               int* __restrict__ flag, int N) {
    __shared__ float Wl[IN_CH * HID];
    __shared__ float xl[BLK_NODES * 33];
    const int t = threadIdx.x;
    if (blockIdx.x == 0 && t == 0) {
        unsigned sdet = 0;
        for (int i = 1; i < 128; i += 2) sdet |= ei[i];
        *flag = (sdet == 0) ? 1 : 0;
    }
    for (int i = t; i < IN_CH * HID / 4; i += 256)
        ((float4*)Wl)[i] = ((const float4*)W)[i];
    const int n0 = blockIdx.x * BLK_NODES;
    const int kq = t & 3;
    const int ng = t >> 2;
    const int k0 = kq * 12;

    float acc[4][12];
#pragma unroll
    for (int i = 0; i < 4; ++i)
#pragma unroll
        for (int j = 0; j < 12; ++j) acc[i][j] = 0.f;

    for (int c0 = 0; c0 < IN_CH; c0 += 32) {
        __syncthreads();
#pragma unroll
        for (int p = 0; p < 8; ++p) {
            int id = t + p * 256;
            int row = id >> 3;
            int seg = id & 7;
            int n = n0 + row;
            float4 v = make_float4(0.f, 0.f, 0.f, 0.f);
            if (n < N) v = ((const float4*)(x + (size_t)n * IN_CH + c0))[seg];
            float* dst = &xl[row * 33 + seg * 4];
            dst[0] = v.x; dst[1] = v.y; dst[2] = v.z; dst[3] = v.w;
        }
        __syncthreads();
#pragma unroll 8
        for (int cc = 0; cc < 32; ++cc) {
            int c = c0 + cc;
            float xv[4];
#pragma unroll
            for (int i = 0; i < 4; ++i) xv[i] = xl[(ng * 4 + i) * 33 + cc];
            const float* wr = &Wl[c * HID + k0];
#pragma unroll
            for (int j = 0; j < 12; ++j) {
                float wv = wr[j];
#pragma unroll
                for (int i = 0; i < 4; ++i) acc[i][j] += xv[i] * wv;
            }
        }
    }
#pragma unroll
    for (int i = 0; i < 4; ++i) {
        int n = n0 + ng * 4 + i;
        if (n < N) {
            uint* dst = (uint*)((char*)h2 + (size_t)n * ROWB) + k0 / 2;
#pragma unroll
            for (int j = 0; j < 6; ++j) {
                __half2 hv = __floats2half2_rn(acc[i][2 * j], acc[i][2 * j + 1]);
                dst[j] = *(const uint*)&hv;
            }
        }
    }
    // zero the 32B row padding (halves 48..63)
#pragma unroll
    for (int p = 0; p < 8; ++p) {
        int id = t + p * 256;
        int row = id >> 3;
        int seg = id & 7;
        int n = n0 + row;
        if (n < N) ((uint*)((char*)h2 + (size_t)n * ROWB))[24 + seg] = 0u;
    }
    // fused attention terms
    float as_[4], ad_[4];
#pragma unroll
    for (int i = 0; i < 4; ++i) {
        float s1 = 0.f, s2 = 0.f;
#pragma unroll
        for (int j = 0; j < 12; ++j) {
            float a = acc[i][j];
            s1 += a * att_src[k0 + j];
            s2 += a * att_dst[k0 + j];
        }
        s1 += __shfl_xor(s1, 1); s1 += __shfl_xor(s1, 2);
        s2 += __shfl_xor(s2, 1); s2 += __shfl_xor(s2, 2);
        as_[i] = s1; ad_[i] = s2;
    }
    if (kq == 0) {
#pragma unroll
        for (int i = 0; i < 4; ++i) {
            int n = n0 + ng * 4 + i;
            if (n < N) { a_src[n] = as_[i]; a_dst[n] = ad_[i]; }
        }
    }
    {
        int n = n0 + t;
        if (n < N) deg[n] = 0;
    }
}

// K3: in-degree count (destination half only); atomic return = rank (ushort).
__global__ __launch_bounds__(256) void k_count(const void* __restrict__ ei,
                                               const int* __restrict__ flag,
                                               int* __restrict__ deg,
                                               unsigned short* __restrict__ rank, int E) {
    int e = blockIdx.x * blockDim.x + threadIdx.x;
    if (e >= E) return;
    int d = (*flag) ? (int)((const long long*)ei)[(size_t)E + e]
                    : ((const int*)ei)[(size_t)E + e];
    rank[e] = (unsigned short)atomicAdd(&deg[d], 1);
}

// K4a: per-block exclusive scan of deg -> rowptr (local), block sums -> bsum
__global__ __launch_bounds__(256) void k_scan_block(const int* __restrict__ deg,
                                                    int* __restrict__ rowptr,
                                                    int* __restrict__ bsum, int N) {
    __shared__ int sm[256];
    const int t = threadIdx.x;
    const int base = blockIdx.x * SCAN_ELEMS + t * 8;
    int v[8];
    int s = 0;
#pragma unroll
    for (int i = 0; i < 8; ++i) {
        v[i] = (base + i < N) ? deg[base + i] : 0;
        s += v[i];
    }
    sm[t] = s;
    __syncthreads();
    for (int off = 1; off < 256; off <<= 1) {
        int y = (t >= off) ? sm[t - off] : 0;
        __syncthreads();
        sm[t] += y;
        __syncthreads();
    }
    int run = sm[t] - s;
#pragma unroll
    for (int i = 0; i < 8; ++i) {
        if (base + i < N) rowptr[base + i] = run;
        run += v[i];
    }
    if (t == 255) bsum[blockIdx.x] = sm[255];
}

// K4b: add block offsets (thread 0 sums the <=48 preceding chunk totals);
// set rowptr[N]=E.
__global__ __launch_bounds__(256) void k_scan_add(int* __restrict__ rowptr,
                                                  const int* __restrict__ bsum, int N, int E) {
    __shared__ int soff;
    const int chunk = (int)(((long long)blockIdx.x * 256) / SCAN_ELEMS);
    if (threadIdx.x == 0) {
        int run = 0;
        for (int b = 0; b < chunk; ++b) run += bsum[b];
        soff = run;
    }
    __syncthreads();
    int i = blockIdx.x * 256 + threadIdx.x;
    if (i == 0) rowptr[N] = E;
    if (i >= N) return;
    rowptr[i] += soff;
}

// K5: scatter edges into CSR (no atomics): pos = rowptr[d] + rank[e].
// NORMAL store (L2 write-allocate): the 6.4MB target fits in L2, lines
// accumulate all slot-writes and write back once (~13MB churn vs ~100MB
// for the nontemporal path that bypassed L2). Positions & content are
// replay-deterministic (rank-based).
__global__ __launch_bounds__(256) void k_scatter(const void* __restrict__ ei,
                                                 const int* __restrict__ flag,
                                                 const int* __restrict__ rowptr,
                                                 const unsigned short* __restrict__ rank,
                                                 unsigned* __restrict__ srcs, int E) {
    int e = blockIdx.x * blockDim.x + threadIdx.x;
    if (e >= E) return;
    int is64 = *flag;
    int s, d;
    load_edge(ei, E, is64, e, s, d);
    int pos = rowptr[d] + (int)rank[e];
    srcs[pos] = (unsigned)s;
}

// K6: fused per-node aggregation + elu + linear + log_softmax. One wave per
// node, 4 waves/block. Per 64-edge chunk: each lane stages one edge (coalesced
// srcs load, one a_src gather, one exp) into LDS as packed (ev,src); the
// 4-slot x 16-lane aggregation loop reads (ev,src) broadcast from LDS and does
// one uint2 gather + 4 fp16->fp32 FMAs. evsum accumulated lane-privately.
__global__ __launch_bounds__(256) void k_gat_node(const int* __restrict__ rowptr,
                                                  const unsigned* __restrict__ srcs,
                                                  const float* __restrict__ a_src,
                                                  const float* __restrict__ a_dst,
                                                  const __half* __restrict__ h2,
                                                  const float* __restrict__ gat_bias,
                                                  const float* __restrict__ lin_W,
                                                  const float* __restrict__ lin_b,
                                                  float* __restrict__ out, int N) {
    __shared__ float Wl[HID * WLP];
    __shared__ float lb[OUT_CH];
    __shared__ float gb[HID];
    __shared__ float o_sm[4][HID];
    __shared__ unsigned long long evb[4][64];
    const int t = threadIdx.x;
    for (int i = t; i < HID * OUT_CH; i += 256) Wl[(i >> 4) * WLP + (i & 15)] = lin_W[i];
    if (t < OUT_CH) lb[t] = lin_b[t];
    if (t >= 64 && t < 64 + HID) gb[t - 64] = gat_bias[t - 64];
    __syncthreads();

    const int wv = t >> 6;
    const int lane = t & 63;
    const int slot = lane >> 4;
    const int c = lane & 15;
    const int n = blockIdx.x * 4 + wv;
    const bool active = n < N;

    if (active) {
        const int base = rowptr[n];
        const int deg = rowptr[n + 1] - base;
        const float adn = a_dst[n];
        const float ev_self = __expf(fminf(leaky(a_src[n] + adn), 50.f));
        const char* hb = (const char*)h2;

        float a0 = 0.f, a1 = 0.f, a2 = 0.f, a3 = 0.f;
        float evsum = (lane == 0) ? ev_self : 0.f;
        if (slot == 0) {
            uint2 hv = *(const uint2*)(hb + (size_t)n * ROWB + 8 * c);
            __half2 h01 = *(const __half2*)&hv.x;
            __half2 h23 = *(const __half2*)&hv.y;
            a0 = ev_self * __low2float(h01);
            a1 = ev_self * __high2float(h01);
            a2 = ev_self * __low2float(h23);
            a3 = ev_self * __high2float(h23);
        }
        for (int c0 = 0; c0 < deg; c0 += 64) {
            int j = c0 + lane;
            unsigned s = 0;
            float ev = 0.f;
            if (j < deg) {
                s = srcs[base + j];
                ev = __expf(fminf(leaky(a_src[s] + adn), 50.f));
            }
            evsum += ev;
            evb[wv][lane] = ((unsigned long long)__float_as_uint(ev) << 32) | s;
            const int cnt = (deg - c0 < 64) ? (deg - c0) : 64;
#pragma unroll 4
            for (int jj = slot; jj < cnt; jj += 4) {
                unsigned long long pr = evb[wv][jj];
                unsigned sj = (unsigned)pr;
                float evj = __uint_as_float((unsigned)(pr >> 32));
                uint2 hv = *(const uint2*)(hb + (size_t)sj * ROWB + 8 * c);
                __half2 h01 = *(const __half2*)&hv.x;
                __half2 h23 = *(const __half2*)&hv.y;
                a0 += evj * __low2float(h01);
                a1 += evj * __high2float(h01);
                a2 += evj * __low2float(h23);
                a3 += evj * __high2float(h23);
            }
        }
#pragma unroll
        for (int off = 1; off < 64; off <<= 1) evsum += __shfl_xor(evsum, off);
        a0 += __shfl_xor(a0, 16); a0 += __shfl_xor(a0, 32);
        a1 += __shfl_xor(a1, 16); a1 += __shfl_xor(a1, 32);
        a2 += __shfl_xor(a2, 16); a2 += __shfl_xor(a2, 32);
        a3 += __shfl_xor(a3, 16); a3 += __shfl_xor(a3, 32);
        const float inv = 1.f / evsum;
        if (slot == 0 && c < 12) {
            float4 v = make_float4(elu(a0 * inv + gb[4 * c + 0]),
                                   elu(a1 * inv + gb[4 * c + 1]),
                                   elu(a2 * inv + gb[4 * c + 2]),
                                   elu(a3 * inv + gb[4 * c + 3]));
            *(float4*)&o_sm[wv][4 * c] = v;
        }
    }
    __syncthreads();

    if (active) {
        const float* o = o_sm[wv];
        float z = 0.f;
#pragma unroll
        for (int i = 0; i < 12; ++i) {
            int k = 12 * slot + i;
            z += o[k] * Wl[k * WLP + c];
        }
        z += __shfl_xor(z, 16); z += __shfl_xor(z, 32);
        z += lb[c];
        float mx = z;
#pragma unroll
        for (int off = 8; off; off >>= 1) mx = fmaxf(mx, __shfl_xor(mx, off, 16));
        float ev = __expf(z - mx);
#pragma unroll
        for (int off = 8; off; off >>= 1) ev += __shfl_xor(ev, off, 16);
        float lse = mx + __logf(ev);
        if (slot == 0) out[(size_t)n * OUT_CH + c] = z - lse;
    }
}

extern "C" void kernel_launch(void* const* d_in, const int* in_sizes, int n_in,
                              void* d_out, int out_size, void* d_ws, size_t ws_size,
                              hipStream_t stream) {
    const float* x = (const float*)d_in[0];
    const void* edge_index = d_in[1];
    const float* W = (const float*)d_in[2];
    const float* att_src = (const float*)d_in[3];
    const float* att_dst = (const float*)d_in[4];
    const float* gat_bias = (const float*)d_in[5];
    const float* lin_W = (const float*)d_in[6];
    const float* lin_b = (const float*)d_in[7];
    float* out = (float*)d_out;

    const int N = in_sizes[0] / IN_CH;
    const int E = in_sizes[1] / 2;

    __half* h2 = (__half*)d_ws;                    // N rows x 128B (12.8MB)
    float* a_src = (float*)((char*)d_ws + (size_t)N * ROWB);  // N
    float* a_dst = a_src + N;                      // N
    int* rowptr = (int*)(a_dst + N);               // N+1
    int* degbuf = rowptr + N + 1;                  // N
    int* bsum = degbuf + N;                        // 64
    int* flag = bsum + 64;                         // 1
    unsigned short* rank = (unsigned short*)(flag + 1);       // E
    unsigned* srcs =
        (unsigned*)(((uintptr_t)(rank + E) + 3) & ~(uintptr_t)3);  // E x 4B

    const int nodeBlocks = (N + 255) / 256;
    const int edgeBlocks = (E + 255) / 256;
    const int scanBlocks = (N + SCAN_ELEMS - 1) / SCAN_ELEMS;

    k_xw<<<(N + BLK_NODES - 1) / BLK_NODES, 256, 0, stream>>>(
        x, W, att_src, att_dst, (const unsigned*)edge_index,
        h2, a_src, a_dst, degbuf, flag, N);
    k_count<<<edgeBlocks, 256, 0, stream>>>(edge_index, flag, degbuf, rank, E);
    k_scan_block<<<scanBlocks, 256, 0, stream>>>(degbuf, rowptr, bsum, N);
    k_scan_add<<<nodeBlocks, 256, 0, stream>>>(rowptr, bsum, N, E);
    k_scatter<<<edgeBlocks, 256, 0, stream>>>(edge_index, flag, rowptr, rank, srcs, E);
    k_gat_node<<<(N + 3) / 4, 256, 0, stream>>>(rowptr, srcs, a_src, a_dst,
                                                h2, gat_bias, lin_W, lin_b, out, N);
}

// Round 14
// 206.881 us; speedup vs baseline: 1.9381x; 1.0065x over previous
//
#include <hip/hip_runtime.h>
#include <hip/hip_fp16.h>

#define IN_CH 128
#define HID 48
#define OUT_CH 16
#define NEG_SLOPE 0.2f
#define SCAN_ELEMS 2048   // per block: 256 threads x 8
#define ROWB 128          // padded h2 row stride in bytes (48 halves + 16 pad)
#define WLP 20            // lin_W LDS pad: 2-way max (free)

__device__ __forceinline__ float leaky(float x) { return x >= 0.f ? x : NEG_SLOPE * x; }
__device__ __forceinline__ float elu(float x) { return x > 0.f ? x : __expf(x) - 1.f; }

__device__ __forceinline__ void load_edge(const void* ei, int E, int is64, int e,
                                          int& s, int& d) {
    if (is64) {
        const long long* p = (const long long*)ei;
        s = (int)p[e];
        d = (int)p[(size_t)E + e];
    } else {
        const int* p = (const int*)ei;
        s = p[e];
        d = p[(size_t)E + e];
    }
}

// K0: zero deg, compute int64/int32 flag.
__global__ __launch_bounds__(256) void k_init(const unsigned* __restrict__ ei,
                                              int* __restrict__ deg,
                                              int* __restrict__ flag, int N) {
    int i = blockIdx.x * blockDim.x + threadIdx.x;
    if (i < N) deg[i] = 0;
    if (i == 0) {
        unsigned sdet = 0;
        for (int k = 1; k < 128; k += 2) sdet |= ei[k];
        *flag = (sdet == 0) ? 1 : 0;
    }
}

// K1: h = x @ W (fp16, 128B-padded rows) fused with a_src/a_dst, plus a
// per-block edge-slice COUNT TAIL (rank[e] = atomicAdd(&deg[d],1)) that
// overlaps other blocks' GEMM work.
#define BLK_NODES 256
__global__ __launch_bounds__(256, 2) void k_xw(const float* __restrict__ x,
                                               const float* __restrict__ W,
                                               const float* __restrict__ att_src,
                                               const float* __restrict__ att_dst,
                                               const void* __restrict__ ei,
                                               __half* __restrict__ h2,
                                               float* __restrict__ a_src,
                                               float* __restrict__ a_dst,
                                               int* __restrict__ deg,
                                               const int* __restrict__ flag,
                                               unsigned short* __restrict__ rank,
                                               int N, int E) {
    __shared__ float Wl[IN_CH * HID];
    __shared__ float xl[BLK_NODES * 33];
    const int t = threadIdx.x;
    for (int i = t; i < IN_CH * HID / 4; i += 256)
        ((float4*)Wl)[i] = ((const float4*)W)[i];
    const int n0 = blockIdx.x * BLK_NODES;
    const int kq = t & 3;
    const int ng = t >> 2;
    const int k0 = kq * 12;

    float acc[4][12];
#pragma unroll
    for (int i = 0; i < 4; ++i)
#pragma unroll
        for (int j = 0; j < 12; ++j) acc[i][j] = 0.f;

    for (int c0 = 0; c0 < IN_CH; c0 += 32) {
        __syncthreads();
#pragma unroll
        for (int p = 0; p < 8; ++p) {
            int id = t + p * 256;
            int row = id >> 3;
            int seg = id & 7;
            int n = n0 + row;
            float4 v = make_float4(0.f, 0.f, 0.f, 0.f);
            if (n < N) v = ((const float4*)(x + (size_t)n * IN_CH + c0))[seg];
            float* dst = &xl[row * 33 + seg * 4];
            dst[0] = v.x; dst[1] = v.y; dst[2] = v.z; dst[3] = v.w;
        }
        __syncthreads();
#pragma unroll 8
        for (int cc = 0; cc < 32; ++cc) {
            int c = c0 + cc;
            float xv[4];
#pragma unroll
            for (int i = 0; i < 4; ++i) xv[i] = xl[(ng * 4 + i) * 33 + cc];
            const float* wr = &Wl[c * HID + k0];
#pragma unroll
            for (int j = 0; j < 12; ++j) {
                float wv = wr[j];
#pragma unroll
                for (int i = 0; i < 4; ++i) acc[i][j] += xv[i] * wv;
            }
        }
    }
#pragma unroll
    for (int i = 0; i < 4; ++i) {
        int n = n0 + ng * 4 + i;
        if (n < N) {
            uint* dst = (uint*)((char*)h2 + (size_t)n * ROWB) + k0 / 2;
#pragma unroll
            for (int j = 0; j < 6; ++j) {
                __half2 hv = __floats2half2_rn(acc[i][2 * j], acc[i][2 * j + 1]);
                dst[j] = *(const uint*)&hv;
            }
        }
    }
    // zero the 32B row padding (halves 48..63)
#pragma unroll
    for (int p = 0; p < 8; ++p) {
        int id = t + p * 256;
        int row = id >> 3;
        int seg = id & 7;
        int n = n0 + row;
        if (n < N) ((uint*)((char*)h2 + (size_t)n * ROWB))[24 + seg] = 0u;
    }
    // fused attention terms
    float as_[4], ad_[4];
#pragma unroll
    for (int i = 0; i < 4; ++i) {
        float s1 = 0.f, s2 = 0.f;
#pragma unroll
        for (int j = 0; j < 12; ++j) {
            float a = acc[i][j];
            s1 += a * att_src[k0 + j];
            s2 += a * att_dst[k0 + j];
        }
        s1 += __shfl_xor(s1, 1); s1 += __shfl_xor(s1, 2);
        s2 += __shfl_xor(s2, 1); s2 += __shfl_xor(s2, 2);
        as_[i] = s1; ad_[i] = s2;
    }
    if (kq == 0) {
#pragma unroll
        for (int i = 0; i < 4; ++i) {
            int n = n0 + ng * 4 + i;
            if (n < N) { a_src[n] = as_[i]; a_dst[n] = ad_[i]; }
        }
    }
    // ---- count tail: this block's slice of edges (deg zeroed by k_init) ----
    {
        const int nb = gridDim.x;
        const int per = (E + nb - 1) / nb;
        const int e0 = blockIdx.x * per;
        const int e1 = (e0 + per < E) ? e0 + per : E;
        const int is64 = *flag;
        for (int e = e0 + t; e < e1; e += 256) {
            int d = is64 ? (int)((const long long*)ei)[(size_t)E + e]
                         : ((const int*)ei)[(size_t)E + e];
            rank[e] = (unsigned short)atomicAdd(&deg[d], 1);
        }
    }
}

// K4a: per-block exclusive scan of deg -> rowptr (local), block sums -> bsum
__global__ __launch_bounds__(256) void k_scan_block(const int* __restrict__ deg,
                                                    int* __restrict__ rowptr,
                                                    int* __restrict__ bsum, int N) {
    __shared__ int sm[256];
    const int t = threadIdx.x;
    const int base = blockIdx.x * SCAN_ELEMS + t * 8;
    int v[8];
    int s = 0;
#pragma unroll
    for (int i = 0; i < 8; ++i) {
        v[i] = (base + i < N) ? deg[base + i] : 0;
        s += v[i];
    }
    sm[t] = s;
    __syncthreads();
    for (int off = 1; off < 256; off <<= 1) {
        int y = (t >= off) ? sm[t - off] : 0;
        __syncthreads();
        sm[t] += y;
        __syncthreads();
    }
    int run = sm[t] - s;
#pragma unroll
    for (int i = 0; i < 8; ++i) {
        if (base + i < N) rowptr[base + i] = run;
        run += v[i];
    }
    if (t == 255) bsum[blockIdx.x] = sm[255];
}

// K4b: add block offsets (thread 0 sums <=48 preceding chunk totals).
__global__ __launch_bounds__(256) void k_scan_add(int* __restrict__ rowptr,
                                                  const int* __restrict__ bsum, int N, int E) {
    __shared__ int soff;
    const int chunk = (int)(((long long)blockIdx.x * 256) / SCAN_ELEMS);
    if (threadIdx.x == 0) {
        int run = 0;
        for (int b = 0; b < chunk; ++b) run += bsum[b];
        soff = run;
    }
    __syncthreads();
    int i = blockIdx.x * 256 + threadIdx.x;
    if (i == 0) rowptr[N] = E;
    if (i >= N) return;
    rowptr[i] += soff;
}

// K5: scatter edges into CSR (no atomics): pos = rowptr[d] + rank[e].
// Normal store (L2 write-allocate; ~13MB churn). Replay-deterministic.
__global__ __launch_bounds__(256) void k_scatter(const void* __restrict__ ei,
                                                 const int* __restrict__ flag,
                                                 const int* __restrict__ rowptr,
                                                 const unsigned short* __restrict__ rank,
                                                 unsigned* __restrict__ srcs, int E) {
    int e = blockIdx.x * blockDim.x + threadIdx.x;
    if (e >= E) return;
    int is64 = *flag;
    int s, d;
    load_edge(ei, E, is64, e, s, d);
    int pos = rowptr[d] + (int)rank[e];
    srcs[pos] = (unsigned)s;
}

// K6: fused per-node aggregation + elu + linear + log_softmax. One wave per
// node, 4 waves/block. LDS-staged (ev,src) per 64-edge chunk; aggregation
// loop software-pipelined 2-deep (gather for jj+4 issued before consuming jj)
// so each lane keeps 2 independent gather chains in flight (8 per wave).
__global__ __launch_bounds__(256) void k_gat_node(const int* __restrict__ rowptr,
                                                  const unsigned* __restrict__ srcs,
                                                  const float* __restrict__ a_src,
                                                  const float* __restrict__ a_dst,
                                                  const __half* __restrict__ h2,
                                                  const float* __restrict__ gat_bias,
                                                  const float* __restrict__ lin_W,
                                                  const float* __restrict__ lin_b,
                                                  float* __restrict__ out, int N) {
    __shared__ float Wl[HID * WLP];
    __shared__ float lb[OUT_CH];
    __shared__ float gb[HID];
    __shared__ float o_sm[4][HID];
    __shared__ unsigned long long evb[4][64];
    const int t = threadIdx.x;
    for (int i = t; i < HID * OUT_CH; i += 256) Wl[(i >> 4) * WLP + (i & 15)] = lin_W[i];
    if (t < OUT_CH) lb[t] = lin_b[t];
    if (t >= 64 && t < 64 + HID) gb[t - 64] = gat_bias[t - 64];
    __syncthreads();

    const int wv = t >> 6;
    const int lane = t & 63;
    const int slot = lane >> 4;
    const int c = lane & 15;
    const int n = blockIdx.x * 4 + wv;
    const bool active = n < N;

    if (active) {
        const int base = rowptr[n];
        const int deg = rowptr[n + 1] - base;
        const float adn = a_dst[n];
        const float ev_self = __expf(fminf(leaky(a_src[n] + adn), 50.f));
        const char* hb = (const char*)h2;

        float a0 = 0.f, a1 = 0.f, a2 = 0.f, a3 = 0.f;
        float evsum = (lane == 0) ? ev_self : 0.f;
        if (slot == 0) {
            uint2 hv = *(const uint2*)(hb + (size_t)n * ROWB + 8 * c);
            __half2 h01 = *(const __half2*)&hv.x;
            __half2 h23 = *(const __half2*)&hv.y;
            a0 = ev_self * __low2float(h01);
            a1 = ev_self * __high2float(h01);
            a2 = ev_self * __low2float(h23);
            a3 = ev_self * __high2float(h23);
        }
        for (int c0 = 0; c0 < deg; c0 += 64) {
            int j = c0 + lane;
            unsigned s = 0;
            float ev = 0.f;
            if (j < deg) {
                s = srcs[base + j];
                ev = __expf(fminf(leaky(a_src[s] + adn), 50.f));
            }
            evsum += ev;
            evb[wv][lane] = ((unsigned long long)__float_as_uint(ev) << 32) | s;
            const int cnt = (deg - c0 < 64) ? (deg - c0) : 64;
            // 2-deep software pipeline over jj = slot, slot+4, ...
            int jj = slot;
            unsigned long long prA = 0;
            uint2 hvA = make_uint2(0u, 0u);
            if (jj < cnt) {
                prA = evb[wv][jj];
                hvA = *(const uint2*)(hb + (size_t)(unsigned)prA * ROWB + 8 * c);
            }
#pragma unroll 2
            for (; jj + 4 < cnt; jj += 4) {
                unsigned long long prB = evb[wv][jj + 4];
                uint2 hvB = *(const uint2*)(hb + (size_t)(unsigned)prB * ROWB + 8 * c);
                float evj = __uint_as_float((unsigned)(prA >> 32));
                __half2 h01 = *(const __half2*)&hvA.x;
                __half2 h23 = *(const __half2*)&hvA.y;
                a0 += evj * __low2float(h01);
                a1 += evj * __high2float(h01);
                a2 += evj * __low2float(h23);
                a3 += evj * __high2float(h23);
                prA = prB; hvA = hvB;
            }
            if (jj < cnt) {
                float evj = __uint_as_float((unsigned)(prA >> 32));
                __half2 h01 = *(const __half2*)&hvA.x;
                __half2 h23 = *(const __half2*)&hvA.y;
                a0 += evj * __low2float(h01);
                a1 += evj * __high2float(h01);
                a2 += evj * __low2float(h23);
                a3 += evj * __high2float(h23);
            }
        }
#pragma unroll
        for (int off = 1; off < 64; off <<= 1) evsum += __shfl_xor(evsum, off);
        a0 += __shfl_xor(a0, 16); a0 += __shfl_xor(a0, 32);
        a1 += __shfl_xor(a1, 16); a1 += __shfl_xor(a1, 32);
        a2 += __shfl_xor(a2, 16); a2 += __shfl_xor(a2, 32);
        a3 += __shfl_xor(a3, 16); a3 += __shfl_xor(a3, 32);
        const float inv = 1.f / evsum;
        if (slot == 0 && c < 12) {
            float4 v = make_float4(elu(a0 * inv + gb[4 * c + 0]),
                                   elu(a1 * inv + gb[4 * c + 1]),
                                   elu(a2 * inv + gb[4 * c + 2]),
                                   elu(a3 * inv + gb[4 * c + 3]));
            *(float4*)&o_sm[wv][4 * c] = v;
        }
    }
    __syncthreads();

    if (active) {
        const float* o = o_sm[wv];
        float z = 0.f;
#pragma unroll
        for (int i = 0; i < 12; ++i) {
            int k = 12 * slot + i;
            z += o[k] * Wl[k * WLP + c];
        }
        z += __shfl_xor(z, 16); z += __shfl_xor(z, 32);
        z += lb[c];
        float mx = z;
#pragma unroll
        for (int off = 8; off; off >>= 1) mx = fmaxf(mx, __shfl_xor(mx, off, 16));
        float ev = __expf(z - mx);
#pragma unroll
        for (int off = 8; off; off >>= 1) ev += __shfl_xor(ev, off, 16);
        float lse = mx + __logf(ev);
        if (slot == 0) out[(size_t)n * OUT_CH + c] = z - lse;
    }
}

extern "C" void kernel_launch(void* const* d_in, const int* in_sizes, int n_in,
                              void* d_out, int out_size, void* d_ws, size_t ws_size,
                              hipStream_t stream) {
    const float* x = (const float*)d_in[0];
    const void* edge_index = d_in[1];
    const float* W = (const float*)d_in[2];
    const float* att_src = (const float*)d_in[3];
    const float* att_dst = (const float*)d_in[4];
    const float* gat_bias = (const float*)d_in[5];
    const float* lin_W = (const float*)d_in[6];
    const float* lin_b = (const float*)d_in[7];
    float* out = (float*)d_out;

    const int N = in_sizes[0] / IN_CH;
    const int E = in_sizes[1] / 2;

    __half* h2 = (__half*)d_ws;                    // N rows x 128B (12.8MB)
    float* a_src = (float*)((char*)d_ws + (size_t)N * ROWB);  // N
    float* a_dst = a_src + N;                      // N
    int* rowptr = (int*)(a_dst + N);               // N+1
    int* degbuf = rowptr + N + 1;                  // N
    int* bsum = degbuf + N;                        // 64
    int* flag = bsum + 64;                         // 1
    unsigned short* rank = (unsigned short*)(flag + 1);       // E
    unsigned* srcs =
        (unsigned*)(((uintptr_t)(rank + E) + 3) & ~(uintptr_t)3);  // E x 4B

    const int nodeBlocks = (N + 255) / 256;
    const int edgeBlocks = (E + 255) / 256;
    const int scanBlocks = (N + SCAN_ELEMS - 1) / SCAN_ELEMS;

    k_init<<<nodeBlocks, 256, 0, stream>>>((const unsigned*)edge_index, degbuf, flag, N);
    k_xw<<<(N + BLK_NODES - 1) / BLK_NODES, 256, 0, stream>>>(
        x, W, att_src, att_dst, edge_index, h2, a_src, a_dst, degbuf, flag, rank, N, E);
    k_scan_block<<<scanBlocks, 256, 0, stream>>>(degbuf, rowptr, bsum, N);
    k_scan_add<<<nodeBlocks, 256, 0, stream>>>(rowptr, bsum, N, E);
    k_scatter<<<edgeBlocks, 256, 0, stream>>>(edge_index, flag, rowptr, rank, srcs, E);
    k_gat_node<<<(N + 3) / 4, 256, 0, stream>>>(rowptr, srcs, a_src, a_dst,
                                                h2, gat_bias, lin_W, lin_b, out, N);
}